// Round 7
// baseline (827.807 us; speedup 1.0000x reference)
//
#include <hip/hip_runtime.h>
#include <math.h>

constexpr int Bn = 4;
constexpr int S  = 64;
constexpr int N  = 4096;  // S*S

#define DEV static __device__ __forceinline__

typedef __attribute__((ext_vector_type(8))) short bf16x8;
typedef __attribute__((ext_vector_type(4))) float f32x4;

DEV unsigned short bfc(float x) {  // f32 -> bf16 RNE
  unsigned u = __float_as_uint(x);
  unsigned r = (u + 0x7FFFu + ((u >> 16) & 1u)) >> 16;
  return (unsigned short)r;
}

DEV float fexp2(float x) {  // raw v_exp_f32
#if __has_builtin(__builtin_amdgcn_exp2f)
  return __builtin_amdgcn_exp2f(x);
#else
  return exp2f(x);
#endif
}

DEV unsigned pkbf(float a, float b) {  // pack two f32 -> packed bf16 pair
#if __has_builtin(__builtin_amdgcn_cvt_pk_bf16_f32)
  auto v = __builtin_amdgcn_cvt_pk_bf16_f32(a, b);
  unsigned u;
  __builtin_memcpy(&u, &v, 4);
  return u;
#else
  return (unsigned)bfc(a) | ((unsigned)bfc(b) << 16);
#endif
}

DEV void fma4(float4& a, float s, const float4 u) {
  a.x = fmaf(s, u.x, a.x); a.y = fmaf(s, u.y, a.y);
  a.z = fmaf(s, u.z, a.z); a.w = fmaf(s, u.w, a.w);
}

// async global->LDS, 16B per lane; lds base must be wave-uniform (lane i lands at +i*16)
DEV void gload_lds16(const unsigned short* g, unsigned short* l) {
  __builtin_amdgcn_global_load_lds(
      (const __attribute__((address_space(1))) void*)g,
      (__attribute__((address_space(3))) void*)l, 16, 0, 0);
}

// ---------------- weight transpose: src[Cout][Cin][T] f32 -> dst[T][Cout][Cin] bf16 ----
__global__ __launch_bounds__(256) void wtr_kernel(const float* __restrict__ src,
                                                  unsigned short* __restrict__ dst,
                                                  int Cout, int Cin, int T) {
  int i = blockIdx.x * 256 + threadIdx.x;
  int ci = i % Cin;
  int r  = i / Cin;
  int t  = r / Cout;
  int co = r - t * Cout;
  dst[i] = bfc(src[((size_t)co * Cin + ci) * T + t]);
}

// ---------------- maxpool 2x2 -> NHWC bf16 padded (halo=1) ----------------
__global__ __launch_bounds__(256) void pool_kernel(const float* __restrict__ x,
                                                   unsigned short* __restrict__ Pp1) {
  int i = blockIdx.x * 256 + threadIdx.x;  // 524288
  int xg = i & 15, y = (i >> 4) & 63, c = (i >> 10) & 127, b = i >> 17;
  const float* s = x + (((size_t)(b * 128 + c) * 128) + 2 * y) * 128 + 8 * xg;
  float4 u0 = *(const float4*)(s), u1 = *(const float4*)(s + 4);
  float4 u2 = *(const float4*)(s + 128), u3 = *(const float4*)(s + 132);
  float m0 = fmaxf(fmaxf(u0.x, u0.y), fmaxf(u2.x, u2.y));
  float m1 = fmaxf(fmaxf(u0.z, u0.w), fmaxf(u2.z, u2.w));
  float m2 = fmaxf(fmaxf(u1.x, u1.y), fmaxf(u3.x, u3.y));
  float m3 = fmaxf(fmaxf(u1.z, u1.w), fmaxf(u3.z, u3.w));
  unsigned short* d = Pp1 + (((size_t)b * 66 + y + 1) * 66 + xg * 4 + 1) * 128 + c;
  d[0] = bfc(m0); d[128] = bfc(m1); d[256] = bfc(m2); d[384] = bfc(m3);
}

// ---------------- dc conv: implicit GEMM, ci-split x2 for occupancy ----------------
template <int CTOT>
__global__ __launch_bounds__(256) void dcconv_kernel(
    const unsigned short* __restrict__ in, const unsigned short* __restrict__ wt,
    float* __restrict__ out) {
  const int Wp = 66, CSEG = CTOT / 2;
  const int w = threadIdx.x >> 6, lane = threadIdx.x & 63;
  const int ln = lane & 15, quad = lane >> 4;
  const int b = blockIdx.z >> 1, h = blockIdx.z & 1, co0 = blockIdx.y * 64;
  const int n0 = blockIdx.x * 128 + w * 32;
  const unsigned short* inb = in + (size_t)b * Wp * Wp * CTOT + h * CSEG;
  const unsigned short* wth = wt + h * CSEG;
  float* outh = out + (size_t)h * 4 * 256 * N;
  size_t pix[2];
#pragma unroll
  for (int j = 0; j < 2; j++) {
    int n = n0 + j * 16 + ln;
    int y = n >> 6, x = n & 63;
    pix[j] = ((size_t)y * Wp + x) * CTOT;
  }
  f32x4 acc[4][2];
#pragma unroll
  for (int i = 0; i < 4; i++)
#pragma unroll
    for (int j = 0; j < 2; j++) acc[i][j] = (f32x4)(0.f);
#pragma unroll
  for (int ky = 0; ky < 3; ky++)
#pragma unroll
    for (int kx = 0; kx < 3; kx++) {
      const size_t toff = ((size_t)ky * Wp + kx) * CTOT;
      const unsigned short* wtap = wth + (size_t)(ky * 3 + kx) * 256 * CTOT;
      for (int kc = 0; kc < CSEG / 32; kc++) {
        const int ko = kc * 32 + quad * 8;
        bf16x8 a[4], bb[2];
#pragma unroll
        for (int i = 0; i < 4; i++)
          a[i] = *(const bf16x8*)(wtap + (size_t)(co0 + i * 16 + ln) * CTOT + ko);
#pragma unroll
        for (int j = 0; j < 2; j++)
          bb[j] = *(const bf16x8*)(inb + pix[j] + toff + ko);
#pragma unroll
        for (int i = 0; i < 4; i++)
#pragma unroll
          for (int j = 0; j < 2; j++)
            acc[i][j] = __builtin_amdgcn_mfma_f32_16x16x32_bf16(a[i], bb[j], acc[i][j], 0, 0, 0);
      }
    }
#pragma unroll
  for (int i = 0; i < 4; i++)
#pragma unroll
    for (int j = 0; j < 2; j++)
#pragma unroll
      for (int r = 0; r < 4; r++)
        outh[((size_t)(b * 256 + co0 + i * 16 + quad * 4 + r)) * N + n0 + j * 16 + ln] =
            acc[i][j][r];
}

// ---------------- all 4 ASPP branches, implicit GEMM on Pp3 (halo=9) ----------------
__global__ __launch_bounds__(256) void branch_kernel(
    const unsigned short* __restrict__ in, const unsigned short* __restrict__ wtall,
    float* __restrict__ br) {
  const int Wp = 82, halo = 9, CIN = 256;
  const int w = threadIdx.x >> 6, lane = threadIdx.x & 63;
  const int ln = lane & 15, quad = lane >> 4;
  const int bb = blockIdx.y;
  const int kbr = bb >> 2, b = bb & 3;
  const int dil = (kbr == 0) ? 1 : 3 * kbr;
  const int klo = (kbr == 0) ? 1 : 0, khi = (kbr == 0) ? 2 : 3;
  const int hd = halo - dil;
  const int cw = (w & 1) * 32, nw = (w >> 1) * 32;
  const int n0 = blockIdx.x * 64 + nw;
  const unsigned short* inb = in + (size_t)b * Wp * Wp * CIN;
  size_t pix[2];
#pragma unroll
  for (int j = 0; j < 2; j++) {
    int n = n0 + j * 16 + ln;
    int y = n >> 6, x = n & 63;
    pix[j] = ((size_t)(y + hd) * Wp + x + hd) * CIN;
  }
  f32x4 acc[2][2];
#pragma unroll
  for (int i = 0; i < 2; i++)
#pragma unroll
    for (int j = 0; j < 2; j++) acc[i][j] = (f32x4)(0.f);
  for (int ky = klo; ky < khi; ky++)
    for (int kx = klo; kx < khi; kx++) {
      const size_t toff = ((size_t)ky * Wp + kx) * dil * CIN;
      const unsigned short* wtap =
          wtall + ((size_t)kbr * 9 + ky * 3 + kx) * 64 * CIN;
      for (int kc = 0; kc < CIN / 32; kc++) {
        const int ko = kc * 32 + quad * 8;
        bf16x8 a[2], bv[2];
#pragma unroll
        for (int i = 0; i < 2; i++)
          a[i] = *(const bf16x8*)(wtap + (size_t)(cw + i * 16 + ln) * CIN + ko);
#pragma unroll
        for (int j = 0; j < 2; j++)
          bv[j] = *(const bf16x8*)(inb + pix[j] + toff + ko);
#pragma unroll
        for (int i = 0; i < 2; i++)
#pragma unroll
          for (int j = 0; j < 2; j++)
            acc[i][j] = __builtin_amdgcn_mfma_f32_16x16x32_bf16(a[i], bv[j], acc[i][j], 0, 0, 0);
      }
    }
#pragma unroll
  for (int i = 0; i < 2; i++)
#pragma unroll
    for (int j = 0; j < 2; j++)
#pragma unroll
      for (int r = 0; r < 4; r++)
        br[((size_t)bb * 64 + cw + i * 16 + quad * 4 + r) * N + n0 + j * 16 + ln] =
            acc[i][j][r];
}

// ---------------- BN stats (single src, for branch outputs) ----------------
__global__ __launch_bounds__(256) void bn_stats_kernel(
    const float* __restrict__ t, const float* __restrict__ gamma,
    const float* __restrict__ beta, float* __restrict__ ss, int C) {
  const int c = blockIdx.x;
  float s = 0.f, s2 = 0.f;
  for (int b = 0; b < Bn; b++) {
    const float* p = t + ((size_t)(b * C + c)) * N;
    for (int i = threadIdx.x; i < N; i += 256) {
      float v = p[i];
      s += v; s2 = fmaf(v, v, s2);
    }
  }
  for (int off = 32; off; off >>= 1) {
    s += __shfl_down(s, off, 64);
    s2 += __shfl_down(s2, off, 64);
  }
  __shared__ float rs[4], rs2[4];
  const int wid = threadIdx.x >> 6, lane = threadIdx.x & 63;
  if (lane == 0) { rs[wid] = s; rs2[wid] = s2; }
  __syncthreads();
  if (threadIdx.x == 0) {
    float S1 = rs[0] + rs[1] + rs[2] + rs[3];
    float S2 = rs2[0] + rs2[1] + rs2[2] + rs2[3];
    const float cnt = (float)(Bn * N);
    float mean = S1 / cnt;
    float var = S2 / cnt - mean * mean;
    float sc = gamma[c] * rsqrtf(var + 1e-5f);
    ss[2 * c] = sc;
    ss[2 * c + 1] = beta[c] - mean * sc;
  }
}

// ---------------- BN stats over sum of two partial buffers (dc convs) ----------------
__global__ __launch_bounds__(256) void bn_stats2_kernel(
    const float* __restrict__ ta, const float* __restrict__ tb,
    const float* __restrict__ gamma, const float* __restrict__ beta,
    float* __restrict__ ss, int C) {
  const int c = blockIdx.x;
  float s = 0.f, s2 = 0.f;
  for (int b = 0; b < Bn; b++) {
    const size_t base = ((size_t)(b * C + c)) * N;
    for (int i = threadIdx.x; i < N; i += 256) {
      float v = ta[base + i] + tb[base + i];
      s += v; s2 = fmaf(v, v, s2);
    }
  }
  for (int off = 32; off; off >>= 1) {
    s += __shfl_down(s, off, 64);
    s2 += __shfl_down(s2, off, 64);
  }
  __shared__ float rs[4], rs2[4];
  const int wid = threadIdx.x >> 6, lane = threadIdx.x & 63;
  if (lane == 0) { rs[wid] = s; rs2[wid] = s2; }
  __syncthreads();
  if (threadIdx.x == 0) {
    float S1 = rs[0] + rs[1] + rs[2] + rs[3];
    float S2 = rs2[0] + rs2[1] + rs2[2] + rs2[3];
    const float cnt = (float)(Bn * N);
    float mean = S1 / cnt;
    float var = S2 / cnt - mean * mean;
    float sc = gamma[c] * rsqrtf(var + 1e-5f);
    ss[2 * c] = sc;
    ss[2 * c + 1] = beta[c] - mean * sc;
  }
}

// ---------------- BN+ReLU (sum of two partials) -> NHWC bf16 padded ----------------
__global__ __launch_bounds__(256) void bn_norm_pad2_kernel(
    const float* __restrict__ ta, const float* __restrict__ tb,
    const float* __restrict__ ss, unsigned short* __restrict__ outp,
    int Wp, int halo) {
  int i = blockIdx.x * 256 + threadIdx.x;
  int n = i & 4095, cg = (i >> 12) & 63, b = i >> 18;
  int c0 = cg * 4;
  ushort4 pk;
  float v0, v1, v2, v3;
  {
    size_t i0 = ((size_t)(b * 256 + c0 + 0)) * N + n;
    size_t i1 = i0 + N, i2 = i1 + N, i3 = i2 + N;
    v0 = fmaxf(fmaf(ta[i0] + tb[i0], ss[2 * (c0 + 0)], ss[2 * (c0 + 0) + 1]), 0.f);
    v1 = fmaxf(fmaf(ta[i1] + tb[i1], ss[2 * (c0 + 1)], ss[2 * (c0 + 1) + 1]), 0.f);
    v2 = fmaxf(fmaf(ta[i2] + tb[i2], ss[2 * (c0 + 2)], ss[2 * (c0 + 2) + 1]), 0.f);
    v3 = fmaxf(fmaf(ta[i3] + tb[i3], ss[2 * (c0 + 3)], ss[2 * (c0 + 3) + 1]), 0.f);
  }
  pk.x = bfc(v0); pk.y = bfc(v1); pk.z = bfc(v2); pk.w = bfc(v3);
  int y = n >> 6, x = n & 63;
  *(ushort4*)(outp + (((size_t)b * Wp + y + halo) * Wp + x + halo) * 256 + c0) = pk;
}

// normalize+ReLU in place (ASPP branch outputs, fp32)
__global__ __launch_bounds__(256) void bn_norm_kernel(
    float* __restrict__ t, const float* __restrict__ ss, int Cmask) {
  int i = blockIdx.x * 256 + threadIdx.x;
  int c = (i >> 12) & Cmask;
  t[i] = fmaxf(fmaf(t[i], ss[2 * c], ss[2 * c + 1]), 0.f);
}

// ---------------- q/k/v 1x1 convs -> bf16 MFMA-layout buffers ----------------
// q is pre-scaled by log2(e) so flash softmax can use raw v_exp_f32 (exp2).
__global__ __launch_bounds__(256) void qkv_kernel(
    const float* __restrict__ br,
    const float* __restrict__ wq, const float* __restrict__ bq,
    const float* __restrict__ wk, const float* __restrict__ bk,
    const float* __restrict__ wv, const float* __restrict__ bvb,
    unsigned short* __restrict__ qTo, unsigned short* __restrict__ kTo,
    unsigned short* __restrict__ vbo) {
  const int bb = blockIdx.z;
  const int p = blockIdx.y >> 2, dg = blockIdx.y & 3;
  const float* w  = p == 0 ? wq : (p == 1 ? wk : wv);
  const float* bi = p == 0 ? bq : (p == 1 ? bk : bvb);
  __shared__ float wl[64 * 16];
  const int d0b = dg * 16;
  for (int i = threadIdx.x; i < 64 * 16; i += 256)
    wl[i] = w[(size_t)(d0b + (i & 15)) * 64 + (i >> 4)];
  __syncthreads();
  const int tn = threadIdx.x & 63, td = threadIdx.x >> 6;
  const int n0 = blockIdx.x * 256 + tn * 4;
  const int d0 = d0b + td * 4;
  const float* inb = br + (size_t)bb * 64 * N;
  float4 acc[4];
#pragma unroll
  for (int j = 0; j < 4; j++) {
    float bvv = bi[d0 + j];
    acc[j] = make_float4(bvv, bvv, bvv, bvv);
  }
  for (int ci = 0; ci < 64; ci++) {
    float4 u = *(const float4*)(inb + (size_t)ci * N + n0);
    float4 wv4 = *(const float4*)(wl + ci * 16 + td * 4);
    fma4(acc[0], wv4.x, u); fma4(acc[1], wv4.y, u);
    fma4(acc[2], wv4.z, u); fma4(acc[3], wv4.w, u);
  }
  if (p == 0) {
    const float LOG2E = 1.4426950408889634f;
#pragma unroll
    for (int j = 0; j < 4; j++) {
      acc[j].x *= LOG2E; acc[j].y *= LOG2E;
      acc[j].z *= LOG2E; acc[j].w *= LOG2E;
    }
  }
  const size_t slab = (size_t)bb * N * 64;
  if (p < 2) {
    unsigned short* o = (p == 0 ? qTo : kTo) + slab;
#pragma unroll
    for (int nn = 0; nn < 4; nn++) {
      ushort4 pk;
      pk.x = bfc(((const float*)&acc[0])[nn]);
      pk.y = bfc(((const float*)&acc[1])[nn]);
      pk.z = bfc(((const float*)&acc[2])[nn]);
      pk.w = bfc(((const float*)&acc[3])[nn]);
      *(ushort4*)(o + (size_t)(n0 + nn) * 64 + d0) = pk;
    }
  } else {
    unsigned short* o = vbo + slab;
#pragma unroll
    for (int j = 0; j < 4; j++) {
      ushort4 pk;
      pk.x = bfc(acc[j].x); pk.y = bfc(acc[j].y);
      pk.z = bfc(acc[j].z); pk.w = bfc(acc[j].w);
      *(ushort4*)(o + (size_t)(d0 + j) * N + n0) = pk;
    }
  }
}

// ---------------- posT[n][d] = rel_w[d][h] + rel_h[d][w], bf16 ----------------
__global__ __launch_bounds__(256) void posT_kernel(
    const float* __restrict__ rel_h, const float* __restrict__ rel_w,
    unsigned short* __restrict__ posT) {
  int i = blockIdx.x * 256 + threadIdx.x;  // 65536
  int n = i >> 4, dq = (i & 15) * 4;
  int h = n >> 6, wc = n & 63;
  ushort4 pk;
  pk.x = bfc(rel_w[(dq + 0) * 64 + h] + rel_h[(dq + 0) * 64 + wc]);
  pk.y = bfc(rel_w[(dq + 1) * 64 + h] + rel_h[(dq + 1) * 64 + wc]);
  pk.z = bfc(rel_w[(dq + 2) * 64 + h] + rel_h[(dq + 2) * 64 + wc]);
  pk.w = bfc(rel_w[(dq + 3) * 64 + h] + rel_h[(dq + 3) * 64 + wc]);
  *(ushort4*)(posT + (size_t)n * 64 + dq) = pk;
}

// ---------------- flash v3: LDS-staged A-side, cell-major (conflict-free) ----------------
// grid (32 m-tiles of 128, 16 pairs, 4 c-splits); 4 waves x 32 m.
// As chunk layout cell-major: cell index p = jt*64 + quad*16 + ln -> 16B cells;
// per-quad read phase hits banks (ln*4)%32 = 2-way = free.
__global__ __launch_bounds__(256, 3) void flash3_kernel(
    const unsigned short* __restrict__ qT, const unsigned short* __restrict__ kT,
    const unsigned short* __restrict__ posT, const unsigned short* __restrict__ vb,
    float* __restrict__ o_part, float* __restrict__ ml) {
  const int bb = blockIdx.y, split = blockIdx.z;
  const size_t slab = (size_t)bb * N * 64;
  const unsigned short* qTs = qT + slab;
  const unsigned short* kTs = kT + slab;
  const unsigned short* vbs = vb + slab;
  const int w = threadIdx.x >> 6, lane = threadIdx.x & 63;
  const int ln = lane & 15, quad = lane >> 4;
  const int m0 = blockIdx.x * 128 + w * 32;  // wave's 32 m-rows (2 frags)
  __shared__ __align__(16) unsigned short As[2][4][256][8];   // 32 KB, cell-major
  __shared__ __align__(16) unsigned short pl[4][2][16][72];   // 18 KB per-wave P

  // wave w stages chunk w; instr j covers rows j*16..j*16+15 (cell-major block)
  const unsigned short* ssrc = (w < 2) ? kTs : qTs;
  const int ksub = (w & 1) * 32 + (lane >> 4) * 8;  // cell = lane>>4
  const int rsub = lane & 15;                       // row within block
  auto stage = [&](int c0, int bufi) {
#pragma unroll
    for (int j = 0; j < 4; j++)
      gload_lds16(ssrc + (size_t)(c0 + j * 16 + rsub) * 64 + ksub,
                  &As[bufi][w][j * 64][0]);
  };

  // m-side B fragments: s<2 -> q rows (log2e-scaled), s>=2 -> pos rows
  bf16x8 bq[4][2];
#pragma unroll
  for (int s = 0; s < 4; s++) {
    const unsigned short* src = (s < 2) ? qTs : posT;
#pragma unroll
    for (int mf = 0; mf < 2; mf++)
      bq[s][mf] = *(const bf16x8*)(src + (size_t)(m0 + mf * 16 + ln) * 64 +
                                   (s & 1) * 32 + quad * 8);
  }

  float m_run[2] = {-3.0e38f, -3.0e38f}, l_run[2] = {0.f, 0.f};
  f32x4 o_acc[4][2];
#pragma unroll
  for (int dt = 0; dt < 4; dt++)
#pragma unroll
    for (int mf = 0; mf < 2; mf++) o_acc[dt][mf] = (f32x4)(0.f);

  const int cbeg = split * 1024;
  stage(cbeg, 0);
  for (int t = 0; t < 16; t++) {
    const int c0 = cbeg + t * 64;
    const int buf = t & 1;
    __syncthreads();               // staging(t) complete
    if (t < 15) stage(c0 + 64, buf ^ 1);  // overlaps compute below
    // ---- S^T from LDS (logits already in log2 domain via scaled q)
    f32x4 st[4][2];
#pragma unroll
    for (int jt = 0; jt < 4; jt++)
#pragma unroll
      for (int mf = 0; mf < 2; mf++) st[jt][mf] = (f32x4)(0.f);
#pragma unroll
    for (int s = 0; s < 4; s++) {
#pragma unroll
      for (int jt = 0; jt < 4; jt++) {
        bf16x8 a = *(const bf16x8*)(&As[buf][s][jt * 64 + quad * 16 + ln][0]);
#pragma unroll
        for (int mf = 0; mf < 2; mf++)
          st[jt][mf] = __builtin_amdgcn_mfma_f32_16x16x32_bf16(a, bq[s][mf], st[jt][mf], 0, 0, 0);
      }
    }
    // ---- online softmax per mf (base-2 domain; raw v_exp_f32)
#pragma unroll
    for (int mf = 0; mf < 2; mf++) {
      float mx = -3.0e38f;
#pragma unroll
      for (int jt = 0; jt < 4; jt++)
#pragma unroll
        for (int r = 0; r < 4; r++) mx = fmaxf(mx, st[jt][mf][r]);
      mx = fmaxf(mx, __shfl_xor(mx, 16, 64));
      mx = fmaxf(mx, __shfl_xor(mx, 32, 64));
      const float m_new = fmaxf(m_run[mf], mx);
      const float alpha = fexp2(m_run[mf] - m_new);
      float psum = 0.f;
#pragma unroll
      for (int jt = 0; jt < 4; jt++) {
        float e0 = fexp2(st[jt][mf][0] - m_new);
        float e1 = fexp2(st[jt][mf][1] - m_new);
        float e2 = fexp2(st[jt][mf][2] - m_new);
        float e3 = fexp2(st[jt][mf][3] - m_new);
        psum += (e0 + e1) + (e2 + e3);
        unsigned lo = pkbf(e0, e1);
        unsigned hi = pkbf(e2, e3);
        *(uint2*)(&pl[w][mf][ln][jt * 16 + quad * 4]) = make_uint2(lo, hi);
      }
      psum += __shfl_xor(psum, 16, 64);
      psum += __shfl_xor(psum, 32, 64);
      l_run[mf] = l_run[mf] * alpha + psum;
      m_run[mf] = m_new;
#pragma unroll
      for (int dt = 0; dt < 4; dt++)
#pragma unroll
        for (int r = 0; r < 4; r++) o_acc[dt][mf][r] *= alpha;
    }
    // ---- PV: O[d][m] += V[d][c] * P[c][m]; V register-direct (L1-shared by waves)
#pragma unroll
    for (int tt = 0; tt < 2; tt++) {
      bf16x8 av[4];
#pragma unroll
      for (int dt = 0; dt < 4; dt++)
        av[dt] = *(const bf16x8*)(vbs + (size_t)(dt * 16 + ln) * N + c0 + tt * 32 + quad * 8);
#pragma unroll
      for (int mf = 0; mf < 2; mf++) {
        bf16x8 bp = *(const bf16x8*)(&pl[w][mf][ln][tt * 32 + quad * 8]);
#pragma unroll
        for (int dt = 0; dt < 4; dt++)
          o_acc[dt][mf] = __builtin_amdgcn_mfma_f32_16x16x32_bf16(av[dt], bp, o_acc[dt][mf], 0, 0, 0);
      }
    }
  }
  // ---- epilogue: unnormalized partials
  float* ob = o_part + ((size_t)(split * 16 + bb) * 64) * N;
#pragma unroll
  for (int dt = 0; dt < 4; dt++)
#pragma unroll
    for (int mf = 0; mf < 2; mf++)
#pragma unroll
      for (int r = 0; r < 4; r++) {
        int d = dt * 16 + quad * 4 + r;
        ob[(size_t)d * N + m0 + mf * 16 + ln] = o_acc[dt][mf][r];
      }
  if (quad == 0) {
#pragma unroll
    for (int mf = 0; mf < 2; mf++) {
      int m = m0 + mf * 16 + ln;
      ml[((size_t)(split * 16 + bb) * 2 + 0) * N + m] = m_run[mf];
      ml[((size_t)(split * 16 + bb) * 2 + 1) * N + m] = l_run[mf];
    }
  }
}

// ---------------- combine weights (log2 domain) ----------------
__global__ __launch_bounds__(256) void wcomb_kernel(const float* __restrict__ ml,
                                                    float* __restrict__ wcb) {
  int i = blockIdx.x * 256 + threadIdx.x;  // 16*4096
  int m = i & 4095, bb = i >> 12;
  float mv[4], lv[4];
#pragma unroll
  for (int s = 0; s < 4; s++) {
    mv[s] = ml[((size_t)(s * 16 + bb) * 2 + 0) * N + m];
    lv[s] = ml[((size_t)(s * 16 + bb) * 2 + 1) * N + m];
  }
  float M = fmaxf(fmaxf(mv[0], mv[1]), fmaxf(mv[2], mv[3]));
  float wsc[4], denom = 0.f;
#pragma unroll
  for (int s = 0; s < 4; s++) {
    wsc[s] = fexp2(mv[s] - M);
    denom = fmaf(wsc[s], lv[s], denom);
  }
  float inv = 1.0f / denom;
#pragma unroll
  for (int s = 0; s < 4; s++)
    wcb[(size_t)(s * 16 + bb) * N + m] = wsc[s] * inv;
}

// ---------------- combine partials -> d_out ----------------
__global__ __launch_bounds__(256) void comb_kernel(const float* __restrict__ o_part,
                                                   const float* __restrict__ wcb,
                                                   float* __restrict__ out) {
  int i = blockIdx.x * 256 + threadIdx.x;
  int m4 = i & 1023, d = (i >> 10) & 63, bb = i >> 16;
  int kbr = bb >> 2, b = bb & 3;
  float4 acc = make_float4(0.f, 0.f, 0.f, 0.f);
#pragma unroll
  for (int s = 0; s < 4; s++) {
    const float4 o = *(const float4*)(o_part + ((size_t)(s * 16 + bb) * 64 + d) * N + m4 * 4);
    const float4 wv = *(const float4*)(wcb + (size_t)(s * 16 + bb) * N + m4 * 4);
    acc.x = fmaf(o.x, wv.x, acc.x); acc.y = fmaf(o.y, wv.y, acc.y);
    acc.z = fmaf(o.z, wv.z, acc.z); acc.w = fmaf(o.w, wv.w, acc.w);
  }
  *(float4*)(out + ((size_t)(b * 256 + kbr * 64 + d)) * N + m4 * 4) = acc;
}

extern "C" void kernel_launch(void* const* d_in, const int* in_sizes, int n_in,
                              void* d_out, int out_size, void* d_ws, size_t ws_size,
                              hipStream_t stream) {
  const float* x      = (const float*)d_in[0];
  const float* dc_w1  = (const float*)d_in[1];
  const float* dc_g1  = (const float*)d_in[3];
  const float* dc_be1 = (const float*)d_in[4];
  const float* dc_w2  = (const float*)d_in[5];
  const float* dc_g2  = (const float*)d_in[7];
  const float* dc_be2 = (const float*)d_in[8];
  const float* aspp_w[4] = {(const float*)d_in[9],  (const float*)d_in[12],
                            (const float*)d_in[15], (const float*)d_in[18]};
  const float* aspp_g[4] = {(const float*)d_in[10], (const float*)d_in[13],
                            (const float*)d_in[16], (const float*)d_in[19]};
  const float* aspp_b[4] = {(const float*)d_in[11], (const float*)d_in[14],
                            (const float*)d_in[17], (const float*)d_in[20]};
  const float* wq = (const float*)d_in[21];
  const float* bq = (const float*)d_in[22];
  const float* wk = (const float*)d_in[23];
  const float* bk = (const float*)d_in[24];
  const float* wv = (const float*)d_in[25];
  const float* bv = (const float*)d_in[26];
  const float* rel_h = (const float*)d_in[27];
  const float* rel_w = (const float*)d_in[28];
  float* out = (float*)d_out;

  float* ws = (float*)d_ws;
  size_t off = 0;
  auto alloc = [&](size_t nf) { float* p = ws + off; off += nf; return p; };
  unsigned short* Pp1 = (unsigned short*)alloc((size_t)4 * 66 * 66 * 128 / 2 + 64);
  unsigned short* Pp2 = (unsigned short*)alloc((size_t)4 * 66 * 66 * 256 / 2 + 64);
  unsigned short* Pp3 = (unsigned short*)alloc((size_t)4 * 82 * 82 * 256 / 2 + 64);
  const size_t HALF = (size_t)4 * 256 * N;
  float* t1   = alloc(2 * HALF);                   // two ci-split partials
  float* br   = alloc((size_t)4 * 4 * 64 * N);
  float* st1  = alloc(512);
  float* st2  = alloc(512);
  float* sta  = alloc(512);
  unsigned short* qT    = (unsigned short*)alloc((size_t)16 * N * 64 / 2);
  unsigned short* kT    = (unsigned short*)alloc((size_t)16 * N * 64 / 2);
  unsigned short* vb    = (unsigned short*)alloc((size_t)16 * N * 64 / 2);
  unsigned short* posT  = (unsigned short*)alloc((size_t)N * 64 / 2);
  unsigned short* wt1   = (unsigned short*)alloc((size_t)9 * 256 * 128 / 2);
  unsigned short* wt2   = (unsigned short*)alloc((size_t)9 * 256 * 256 / 2);
  unsigned short* wtbr  = (unsigned short*)alloc((size_t)4 * 9 * 64 * 256 / 2);
  float* o_part = alloc((size_t)4 * 16 * 64 * N);  // 67 MB
  float* mlb    = alloc((size_t)4 * 16 * 2 * N);
  float* wcb    = alloc((size_t)4 * 16 * N);

  hipMemsetAsync(Pp1, 0, (size_t)4 * 66 * 66 * 128 * 2, stream);
  hipMemsetAsync(Pp2, 0, (size_t)4 * 66 * 66 * 256 * 2, stream);
  hipMemsetAsync(Pp3, 0, (size_t)4 * 82 * 82 * 256 * 2, stream);
  hipMemsetAsync(wtbr, 0, (size_t)4 * 9 * 64 * 256 * 2, stream);

  // weight prep
  wtr_kernel<<<(9 * 256 * 128) / 256, 256, 0, stream>>>(dc_w1, wt1, 256, 128, 9);
  wtr_kernel<<<(9 * 256 * 256) / 256, 256, 0, stream>>>(dc_w2, wt2, 256, 256, 9);
  wtr_kernel<<<(64 * 256) / 256, 256, 0, stream>>>(
      aspp_w[0], wtbr + (size_t)4 * 64 * 256, 64, 256, 1);
  for (int kbr = 1; kbr < 4; kbr++)
    wtr_kernel<<<(9 * 64 * 256) / 256, 256, 0, stream>>>(
        aspp_w[kbr], wtbr + (size_t)kbr * 9 * 64 * 256, 64, 256, 9);

  pool_kernel<<<2048, 256, 0, stream>>>(x, Pp1);

  dcconv_kernel<128><<<dim3(32, 4, 8), 256, 0, stream>>>(Pp1, wt1, t1);
  bn_stats2_kernel<<<256, 256, 0, stream>>>(t1, t1 + HALF, dc_g1, dc_be1, st1, 256);
  bn_norm_pad2_kernel<<<4096, 256, 0, stream>>>(t1, t1 + HALF, st1, Pp2, 66, 1);
  dcconv_kernel<256><<<dim3(32, 4, 8), 256, 0, stream>>>(Pp2, wt2, t1);
  bn_stats2_kernel<<<256, 256, 0, stream>>>(t1, t1 + HALF, dc_g2, dc_be2, st2, 256);
  bn_norm_pad2_kernel<<<4096, 256, 0, stream>>>(t1, t1 + HALF, st2, Pp3, 82, 9);

  branch_kernel<<<dim3(64, 16), 256, 0, stream>>>(Pp3, wtbr, br);
  for (int kbr = 0; kbr < 4; kbr++) {
    bn_stats_kernel<<<64, 256, 0, stream>>>(br + (size_t)kbr * 1048576,
                                            aspp_g[kbr], aspp_b[kbr],
                                            sta + kbr * 128, 64);
    bn_norm_kernel<<<4096, 256, 0, stream>>>(br + (size_t)kbr * 1048576,
                                             sta + kbr * 128, 63);
  }

  qkv_kernel<<<dim3(16, 12, 16), 256, 0, stream>>>(br, wq, bq, wk, bk, wv, bv,
                                                   qT, kT, vb);
  posT_kernel<<<256, 256, 0, stream>>>(rel_h, rel_w, posT);

  flash3_kernel<<<dim3(32, 16, 4), 256, 0, stream>>>(qT, kT, posT, vb, o_part, mlb);
  wcomb_kernel<<<256, 256, 0, stream>>>(mlb, wcb);
  comb_kernel<<<4096, 256, 0, stream>>>(o_part, wcb, out);
}

// Round 8
// 807.665 us; speedup vs baseline: 1.0249x; 1.0249x over previous
//
#include <hip/hip_runtime.h>
#include <math.h>

constexpr int Bn = 4;
constexpr int S  = 64;
constexpr int N  = 4096;  // S*S

#define DEV static __device__ __forceinline__

typedef __attribute__((ext_vector_type(8))) short bf16x8;
typedef __attribute__((ext_vector_type(4))) float f32x4;

DEV unsigned short bfc(float x) {  // f32 -> bf16 RNE
  unsigned u = __float_as_uint(x);
  unsigned r = (u + 0x7FFFu + ((u >> 16) & 1u)) >> 16;
  return (unsigned short)r;
}

DEV float fexp2(float x) {  // raw v_exp_f32
#if __has_builtin(__builtin_amdgcn_exp2f)
  return __builtin_amdgcn_exp2f(x);
#else
  return exp2f(x);
#endif
}

DEV unsigned pkbf(float a, float b) {  // pack two f32 -> packed bf16 pair
#if __has_builtin(__builtin_amdgcn_cvt_pk_bf16_f32)
  auto v = __builtin_amdgcn_cvt_pk_bf16_f32(a, b);
  unsigned u;
  __builtin_memcpy(&u, &v, 4);
  return u;
#else
  return (unsigned)bfc(a) | ((unsigned)bfc(b) << 16);
#endif
}

DEV void fma4(float4& a, float s, const float4 u) {
  a.x = fmaf(s, u.x, a.x); a.y = fmaf(s, u.y, a.y);
  a.z = fmaf(s, u.z, a.z); a.w = fmaf(s, u.w, a.w);
}

// async global->LDS, 16B per lane; lds base wave-uniform (lane i lands at +i*16)
DEV void gload_lds16(const unsigned short* g, unsigned short* l) {
  __builtin_amdgcn_global_load_lds(
      (const __attribute__((address_space(1))) void*)g,
      (__attribute__((address_space(3))) void*)l, 16, 0, 0);
}

// ---------------- weight transpose: src[Cout][Cin][T] f32 -> dst[T][Cout][Cin] bf16 ----
__global__ __launch_bounds__(256) void wtr_kernel(const float* __restrict__ src,
                                                  unsigned short* __restrict__ dst,
                                                  int Cout, int Cin, int T) {
  int i = blockIdx.x * 256 + threadIdx.x;
  int ci = i % Cin;
  int r  = i / Cin;
  int t  = r / Cout;
  int co = r - t * Cout;
  dst[i] = bfc(src[((size_t)co * Cin + ci) * T + t]);
}

// ---------------- maxpool 2x2 -> NHWC bf16 padded (halo=1) ----------------
__global__ __launch_bounds__(256) void pool_kernel(const float* __restrict__ x,
                                                   unsigned short* __restrict__ Pp1) {
  int i = blockIdx.x * 256 + threadIdx.x;  // 524288
  int xg = i & 15, y = (i >> 4) & 63, c = (i >> 10) & 127, b = i >> 17;
  const float* s = x + (((size_t)(b * 128 + c) * 128) + 2 * y) * 128 + 8 * xg;
  float4 u0 = *(const float4*)(s), u1 = *(const float4*)(s + 4);
  float4 u2 = *(const float4*)(s + 128), u3 = *(const float4*)(s + 132);
  float m0 = fmaxf(fmaxf(u0.x, u0.y), fmaxf(u2.x, u2.y));
  float m1 = fmaxf(fmaxf(u0.z, u0.w), fmaxf(u2.z, u2.w));
  float m2 = fmaxf(fmaxf(u1.x, u1.y), fmaxf(u3.x, u3.y));
  float m3 = fmaxf(fmaxf(u1.z, u1.w), fmaxf(u3.z, u3.w));
  unsigned short* d = Pp1 + (((size_t)b * 66 + y + 1) * 66 + xg * 4 + 1) * 128 + c;
  d[0] = bfc(m0); d[128] = bfc(m1); d[256] = bfc(m2); d[384] = bfc(m3);
}

// ---------------- dc conv: implicit GEMM, ci-split x2 for occupancy ----------------
template <int CTOT>
__global__ __launch_bounds__(256) void dcconv_kernel(
    const unsigned short* __restrict__ in, const unsigned short* __restrict__ wt,
    float* __restrict__ out) {
  const int Wp = 66, CSEG = CTOT / 2;
  const int w = threadIdx.x >> 6, lane = threadIdx.x & 63;
  const int ln = lane & 15, quad = lane >> 4;
  const int b = blockIdx.z >> 1, h = blockIdx.z & 1, co0 = blockIdx.y * 64;
  const int n0 = blockIdx.x * 128 + w * 32;
  const unsigned short* inb = in + (size_t)b * Wp * Wp * CTOT + h * CSEG;
  const unsigned short* wth = wt + h * CSEG;
  float* outh = out + (size_t)h * 4 * 256 * N;
  size_t pix[2];
#pragma unroll
  for (int j = 0; j < 2; j++) {
    int n = n0 + j * 16 + ln;
    int y = n >> 6, x = n & 63;
    pix[j] = ((size_t)y * Wp + x) * CTOT;
  }
  f32x4 acc[4][2];
#pragma unroll
  for (int i = 0; i < 4; i++)
#pragma unroll
    for (int j = 0; j < 2; j++) acc[i][j] = (f32x4)(0.f);
#pragma unroll
  for (int ky = 0; ky < 3; ky++)
#pragma unroll
    for (int kx = 0; kx < 3; kx++) {
      const size_t toff = ((size_t)ky * Wp + kx) * CTOT;
      const unsigned short* wtap = wth + (size_t)(ky * 3 + kx) * 256 * CTOT;
      for (int kc = 0; kc < CSEG / 32; kc++) {
        const int ko = kc * 32 + quad * 8;
        bf16x8 a[4], bb[2];
#pragma unroll
        for (int i = 0; i < 4; i++)
          a[i] = *(const bf16x8*)(wtap + (size_t)(co0 + i * 16 + ln) * CTOT + ko);
#pragma unroll
        for (int j = 0; j < 2; j++)
          bb[j] = *(const bf16x8*)(inb + pix[j] + toff + ko);
#pragma unroll
        for (int i = 0; i < 4; i++)
#pragma unroll
          for (int j = 0; j < 2; j++)
            acc[i][j] = __builtin_amdgcn_mfma_f32_16x16x32_bf16(a[i], bb[j], acc[i][j], 0, 0, 0);
      }
    }
#pragma unroll
  for (int i = 0; i < 4; i++)
#pragma unroll
    for (int j = 0; j < 2; j++)
#pragma unroll
      for (int r = 0; r < 4; r++)
        outh[((size_t)(b * 256 + co0 + i * 16 + quad * 4 + r)) * N + n0 + j * 16 + ln] =
            acc[i][j][r];
}

// ---------------- ASPP branches v2: dcconv-shape, ci-split x2 ----------------
// grid (32 n-tiles of 128, 16 bb, 2 ci-halves); 4 waves x (64co x 32n).
// brp[h][bb][64][N] fp32 partials.
__global__ __launch_bounds__(256) void branch2_kernel(
    const unsigned short* __restrict__ in, const unsigned short* __restrict__ wtall,
    float* __restrict__ brp) {
  const int Wp = 82, halo = 9, CIN = 256, CSEG = 128;
  const int w = threadIdx.x >> 6, lane = threadIdx.x & 63;
  const int ln = lane & 15, quad = lane >> 4;
  const int bb = blockIdx.y, h = blockIdx.z;
  const int kbr = bb >> 2, b = bb & 3;
  const int dil = (kbr == 0) ? 1 : 3 * kbr;
  const int klo = (kbr == 0) ? 1 : 0, khi = (kbr == 0) ? 2 : 3;
  const int hd = halo - dil;
  const int n0 = blockIdx.x * 128 + w * 32;
  const unsigned short* inb = in + (size_t)b * Wp * Wp * CIN + h * CSEG;
  const unsigned short* wth = wtall + (size_t)kbr * 9 * 64 * CIN + h * CSEG;
  float* outh = brp + (size_t)h * 16 * 64 * N;
  size_t pix[2];
#pragma unroll
  for (int j = 0; j < 2; j++) {
    int n = n0 + j * 16 + ln;
    int y = n >> 6, x = n & 63;
    pix[j] = ((size_t)(y + hd) * Wp + x + hd) * CIN;
  }
  f32x4 acc[4][2];
#pragma unroll
  for (int i = 0; i < 4; i++)
#pragma unroll
    for (int j = 0; j < 2; j++) acc[i][j] = (f32x4)(0.f);
  for (int ky = klo; ky < khi; ky++)
    for (int kx = klo; kx < khi; kx++) {
      const size_t toff = ((size_t)ky * Wp + kx) * dil * CIN;
      const unsigned short* wtap = wth + (size_t)(ky * 3 + kx) * 64 * CIN;
      for (int kc = 0; kc < CSEG / 32; kc++) {
        const int ko = kc * 32 + quad * 8;
        bf16x8 a[4], bv[2];
#pragma unroll
        for (int i = 0; i < 4; i++)
          a[i] = *(const bf16x8*)(wtap + (size_t)(i * 16 + ln) * CIN + ko);
#pragma unroll
        for (int j = 0; j < 2; j++)
          bv[j] = *(const bf16x8*)(inb + pix[j] + toff + ko);
#pragma unroll
        for (int i = 0; i < 4; i++)
#pragma unroll
          for (int j = 0; j < 2; j++)
            acc[i][j] = __builtin_amdgcn_mfma_f32_16x16x32_bf16(a[i], bv[j], acc[i][j], 0, 0, 0);
      }
    }
#pragma unroll
  for (int i = 0; i < 4; i++)
#pragma unroll
    for (int j = 0; j < 2; j++)
#pragma unroll
      for (int r = 0; r < 4; r++)
        outh[((size_t)bb * 64 + i * 16 + quad * 4 + r) * N + n0 + j * 16 + ln] =
            acc[i][j][r];
}

// ---------------- BN stats over sum of two partial buffers ----------------
__global__ __launch_bounds__(256) void bn_stats2_kernel(
    const float* __restrict__ ta, const float* __restrict__ tb,
    const float* __restrict__ gamma, const float* __restrict__ beta,
    float* __restrict__ ss, int C) {
  const int c = blockIdx.x;
  float s = 0.f, s2 = 0.f;
  for (int b = 0; b < Bn; b++) {
    const size_t base = ((size_t)(b * C + c)) * N;
    for (int i = threadIdx.x; i < N; i += 256) {
      float v = ta[base + i] + tb[base + i];
      s += v; s2 = fmaf(v, v, s2);
    }
  }
  for (int off = 32; off; off >>= 1) {
    s += __shfl_down(s, off, 64);
    s2 += __shfl_down(s2, off, 64);
  }
  __shared__ float rs[4], rs2[4];
  const int wid = threadIdx.x >> 6, lane = threadIdx.x & 63;
  if (lane == 0) { rs[wid] = s; rs2[wid] = s2; }
  __syncthreads();
  if (threadIdx.x == 0) {
    float S1 = rs[0] + rs[1] + rs[2] + rs[3];
    float S2 = rs2[0] + rs2[1] + rs2[2] + rs2[3];
    const float cnt = (float)(Bn * N);
    float mean = S1 / cnt;
    float var = S2 / cnt - mean * mean;
    float sc = gamma[c] * rsqrtf(var + 1e-5f);
    ss[2 * c] = sc;
    ss[2 * c + 1] = beta[c] - mean * sc;
  }
}

// ---------------- BN+ReLU (sum of two partials) -> NHWC bf16 padded ----------------
__global__ __launch_bounds__(256) void bn_norm_pad2_kernel(
    const float* __restrict__ ta, const float* __restrict__ tb,
    const float* __restrict__ ss, unsigned short* __restrict__ outp,
    int Wp, int halo) {
  int i = blockIdx.x * 256 + threadIdx.x;
  int n = i & 4095, cg = (i >> 12) & 63, b = i >> 18;
  int c0 = cg * 4;
  ushort4 pk;
  float v0, v1, v2, v3;
  {
    size_t i0 = ((size_t)(b * 256 + c0 + 0)) * N + n;
    size_t i1 = i0 + N, i2 = i1 + N, i3 = i2 + N;
    v0 = fmaxf(fmaf(ta[i0] + tb[i0], ss[2 * (c0 + 0)], ss[2 * (c0 + 0) + 1]), 0.f);
    v1 = fmaxf(fmaf(ta[i1] + tb[i1], ss[2 * (c0 + 1)], ss[2 * (c0 + 1) + 1]), 0.f);
    v2 = fmaxf(fmaf(ta[i2] + tb[i2], ss[2 * (c0 + 2)], ss[2 * (c0 + 2) + 1]), 0.f);
    v3 = fmaxf(fmaf(ta[i3] + tb[i3], ss[2 * (c0 + 3)], ss[2 * (c0 + 3) + 1]), 0.f);
  }
  pk.x = bfc(v0); pk.y = bfc(v1); pk.z = bfc(v2); pk.w = bfc(v3);
  int y = n >> 6, x = n & 63;
  *(ushort4*)(outp + (((size_t)b * Wp + y + halo) * Wp + x + halo) * 256 + c0) = pk;
}

// ---------------- BN+ReLU sum of two branch partials, in place into ta ----------------
__global__ __launch_bounds__(256) void bn_norm2_kernel(
    float* __restrict__ ta, const float* __restrict__ tb,
    const float* __restrict__ ss) {
  int i = blockIdx.x * 256 + threadIdx.x;  // 1048576 per kbr slab
  int c = (i >> 12) & 63;
  ta[i] = fmaxf(fmaf(ta[i] + tb[i], ss[2 * c], ss[2 * c + 1]), 0.f);
}

// ---------------- q/k/v 1x1 convs -> bf16 MFMA-layout buffers ----------------
// q is pre-scaled by log2(e) so flash softmax can use raw v_exp_f32 (exp2).
__global__ __launch_bounds__(256) void qkv_kernel(
    const float* __restrict__ br,
    const float* __restrict__ wq, const float* __restrict__ bq,
    const float* __restrict__ wk, const float* __restrict__ bk,
    const float* __restrict__ wv, const float* __restrict__ bvb,
    unsigned short* __restrict__ qTo, unsigned short* __restrict__ kTo,
    unsigned short* __restrict__ vbo) {
  const int bb = blockIdx.z;
  const int p = blockIdx.y >> 2, dg = blockIdx.y & 3;
  const float* w  = p == 0 ? wq : (p == 1 ? wk : wv);
  const float* bi = p == 0 ? bq : (p == 1 ? bk : bvb);
  __shared__ float wl[64 * 16];
  const int d0b = dg * 16;
  for (int i = threadIdx.x; i < 64 * 16; i += 256)
    wl[i] = w[(size_t)(d0b + (i & 15)) * 64 + (i >> 4)];
  __syncthreads();
  const int tn = threadIdx.x & 63, td = threadIdx.x >> 6;
  const int n0 = blockIdx.x * 256 + tn * 4;
  const int d0 = d0b + td * 4;
  const float* inb = br + (size_t)bb * 64 * N;
  float4 acc[4];
#pragma unroll
  for (int j = 0; j < 4; j++) {
    float bvv = bi[d0 + j];
    acc[j] = make_float4(bvv, bvv, bvv, bvv);
  }
  for (int ci = 0; ci < 64; ci++) {
    float4 u = *(const float4*)(inb + (size_t)ci * N + n0);
    float4 wv4 = *(const float4*)(wl + ci * 16 + td * 4);
    fma4(acc[0], wv4.x, u); fma4(acc[1], wv4.y, u);
    fma4(acc[2], wv4.z, u); fma4(acc[3], wv4.w, u);
  }
  if (p == 0) {
    const float LOG2E = 1.4426950408889634f;
#pragma unroll
    for (int j = 0; j < 4; j++) {
      acc[j].x *= LOG2E; acc[j].y *= LOG2E;
      acc[j].z *= LOG2E; acc[j].w *= LOG2E;
    }
  }
  const size_t slab = (size_t)bb * N * 64;
  if (p < 2) {
    unsigned short* o = (p == 0 ? qTo : kTo) + slab;
#pragma unroll
    for (int nn = 0; nn < 4; nn++) {
      ushort4 pk;
      pk.x = bfc(((const float*)&acc[0])[nn]);
      pk.y = bfc(((const float*)&acc[1])[nn]);
      pk.z = bfc(((const float*)&acc[2])[nn]);
      pk.w = bfc(((const float*)&acc[3])[nn]);
      *(ushort4*)(o + (size_t)(n0 + nn) * 64 + d0) = pk;
    }
  } else {
    unsigned short* o = vbo + slab;
#pragma unroll
    for (int j = 0; j < 4; j++) {
      ushort4 pk;
      pk.x = bfc(acc[j].x); pk.y = bfc(acc[j].y);
      pk.z = bfc(acc[j].z); pk.w = bfc(acc[j].w);
      *(ushort4*)(o + (size_t)(d0 + j) * N + n0) = pk;
    }
  }
}

// ---------------- posT[n][d] = rel_w[d][h] + rel_h[d][w], bf16 ----------------
__global__ __launch_bounds__(256) void posT_kernel(
    const float* __restrict__ rel_h, const float* __restrict__ rel_w,
    unsigned short* __restrict__ posT) {
  int i = blockIdx.x * 256 + threadIdx.x;  // 65536
  int n = i >> 4, dq = (i & 15) * 4;
  int h = n >> 6, wc = n & 63;
  ushort4 pk;
  pk.x = bfc(rel_w[(dq + 0) * 64 + h] + rel_h[(dq + 0) * 64 + wc]);
  pk.y = bfc(rel_w[(dq + 1) * 64 + h] + rel_h[(dq + 1) * 64 + wc]);
  pk.z = bfc(rel_w[(dq + 2) * 64 + h] + rel_h[(dq + 2) * 64 + wc]);
  pk.w = bfc(rel_w[(dq + 3) * 64 + h] + rel_h[(dq + 3) * 64 + wc]);
  *(ushort4*)(posT + (size_t)n * 64 + dq) = pk;
}

// ---------------- flash v3: LDS-staged A-side (R6 coalesced layout) + exp2 softmax ----
// grid (32 m-tiles of 128, 16 pairs, 4 c-splits); 4 waves x 32 m.
__global__ __launch_bounds__(256, 3) void flash3_kernel(
    const unsigned short* __restrict__ qT, const unsigned short* __restrict__ kT,
    const unsigned short* __restrict__ posT, const unsigned short* __restrict__ vb,
    float* __restrict__ o_part, float* __restrict__ ml) {
  const int bb = blockIdx.y, split = blockIdx.z;
  const size_t slab = (size_t)bb * N * 64;
  const unsigned short* qTs = qT + slab;
  const unsigned short* kTs = kT + slab;
  const unsigned short* vbs = vb + slab;
  const int w = threadIdx.x >> 6, lane = threadIdx.x & 63;
  const int ln = lane & 15, quad = lane >> 4;
  const int m0 = blockIdx.x * 128 + w * 32;  // wave's 32 m-rows (2 frags)
  __shared__ __align__(16) unsigned short As[2][4][64][32];   // 32 KB
  __shared__ __align__(16) unsigned short pl[4][2][16][72];   // 18 KB per-wave P

  // wave w stages chunk w: coalesced — 4 lanes cover 64 B of one row
  const unsigned short* ssrc = (w < 2) ? kTs : qTs;
  const int ksub = (w & 1) * 32 + (lane & 3) * 8;
  const int rsub = lane >> 2;
  auto stage = [&](int c0, int bufi) {
#pragma unroll
    for (int j = 0; j < 4; j++)
      gload_lds16(ssrc + (size_t)(c0 + j * 16 + rsub) * 64 + ksub,
                  &As[bufi][w][j * 16][0]);
  };

  // m-side B fragments: s<2 -> q rows (log2e-scaled), s>=2 -> pos rows
  bf16x8 bq[4][2];
#pragma unroll
  for (int s = 0; s < 4; s++) {
    const unsigned short* src = (s < 2) ? qTs : posT;
#pragma unroll
    for (int mf = 0; mf < 2; mf++)
      bq[s][mf] = *(const bf16x8*)(src + (size_t)(m0 + mf * 16 + ln) * 64 +
                                   (s & 1) * 32 + quad * 8);
  }

  float m_run[2] = {-3.0e38f, -3.0e38f}, l_run[2] = {0.f, 0.f};
  f32x4 o_acc[4][2];
#pragma unroll
  for (int dt = 0; dt < 4; dt++)
#pragma unroll
    for (int mf = 0; mf < 2; mf++) o_acc[dt][mf] = (f32x4)(0.f);

  const int cbeg = split * 1024;
  stage(cbeg, 0);
  for (int t = 0; t < 16; t++) {
    const int c0 = cbeg + t * 64;
    const int buf = t & 1;
    __syncthreads();               // staging(t) complete
    if (t < 15) stage(c0 + 64, buf ^ 1);  // overlaps compute below
    // ---- S^T from LDS (logits in log2 domain via scaled q)
    f32x4 st[4][2];
#pragma unroll
    for (int jt = 0; jt < 4; jt++)
#pragma unroll
      for (int mf = 0; mf < 2; mf++) st[jt][mf] = (f32x4)(0.f);
#pragma unroll
    for (int s = 0; s < 4; s++) {
#pragma unroll
      for (int jt = 0; jt < 4; jt++) {
        bf16x8 a = *(const bf16x8*)(&As[buf][s][jt * 16 + ln][quad * 8]);
#pragma unroll
        for (int mf = 0; mf < 2; mf++)
          st[jt][mf] = __builtin_amdgcn_mfma_f32_16x16x32_bf16(a, bq[s][mf], st[jt][mf], 0, 0, 0);
      }
    }
    // ---- online softmax per mf (base-2 domain; raw v_exp_f32)
#pragma unroll
    for (int mf = 0; mf < 2; mf++) {
      float mx = -3.0e38f;
#pragma unroll
      for (int jt = 0; jt < 4; jt++)
#pragma unroll
        for (int r = 0; r < 4; r++) mx = fmaxf(mx, st[jt][mf][r]);
      mx = fmaxf(mx, __shfl_xor(mx, 16, 64));
      mx = fmaxf(mx, __shfl_xor(mx, 32, 64));
      const float m_new = fmaxf(m_run[mf], mx);
      const float alpha = fexp2(m_run[mf] - m_new);
      float psum = 0.f;
#pragma unroll
      for (int jt = 0; jt < 4; jt++) {
        float e0 = fexp2(st[jt][mf][0] - m_new);
        float e1 = fexp2(st[jt][mf][1] - m_new);
        float e2 = fexp2(st[jt][mf][2] - m_new);
        float e3 = fexp2(st[jt][mf][3] - m_new);
        psum += (e0 + e1) + (e2 + e3);
        unsigned lo = pkbf(e0, e1);
        unsigned hi = pkbf(e2, e3);
        *(uint2*)(&pl[w][mf][ln][jt * 16 + quad * 4]) = make_uint2(lo, hi);
      }
      psum += __shfl_xor(psum, 16, 64);
      psum += __shfl_xor(psum, 32, 64);
      l_run[mf] = l_run[mf] * alpha + psum;
      m_run[mf] = m_new;
#pragma unroll
      for (int dt = 0; dt < 4; dt++)
#pragma unroll
        for (int r = 0; r < 4; r++) o_acc[dt][mf][r] *= alpha;
    }
    // ---- PV: O[d][m] += V[d][c] * P[c][m]; V register-direct (L1-shared by waves)
#pragma unroll
    for (int tt = 0; tt < 2; tt++) {
      bf16x8 av[4];
#pragma unroll
      for (int dt = 0; dt < 4; dt++)
        av[dt] = *(const bf16x8*)(vbs + (size_t)(dt * 16 + ln) * N + c0 + tt * 32 + quad * 8);
#pragma unroll
      for (int mf = 0; mf < 2; mf++) {
        bf16x8 bp = *(const bf16x8*)(&pl[w][mf][ln][tt * 32 + quad * 8]);
#pragma unroll
        for (int dt = 0; dt < 4; dt++)
          o_acc[dt][mf] = __builtin_amdgcn_mfma_f32_16x16x32_bf16(av[dt], bp, o_acc[dt][mf], 0, 0, 0);
      }
    }
  }
  // ---- epilogue: unnormalized partials
  float* ob = o_part + ((size_t)(split * 16 + bb) * 64) * N;
#pragma unroll
  for (int dt = 0; dt < 4; dt++)
#pragma unroll
    for (int mf = 0; mf < 2; mf++)
#pragma unroll
      for (int r = 0; r < 4; r++) {
        int d = dt * 16 + quad * 4 + r;
        ob[(size_t)d * N + m0 + mf * 16 + ln] = o_acc[dt][mf][r];
      }
  if (quad == 0) {
#pragma unroll
    for (int mf = 0; mf < 2; mf++) {
      int m = m0 + mf * 16 + ln;
      ml[((size_t)(split * 16 + bb) * 2 + 0) * N + m] = m_run[mf];
      ml[((size_t)(split * 16 + bb) * 2 + 1) * N + m] = l_run[mf];
    }
  }
}

// ---------------- combine weights (log2 domain) ----------------
__global__ __launch_bounds__(256) void wcomb_kernel(const float* __restrict__ ml,
                                                    float* __restrict__ wcb) {
  int i = blockIdx.x * 256 + threadIdx.x;  // 16*4096
  int m = i & 4095, bb = i >> 12;
  float mv[4], lv[4];
#pragma unroll
  for (int s = 0; s < 4; s++) {
    mv[s] = ml[((size_t)(s * 16 + bb) * 2 + 0) * N + m];
    lv[s] = ml[((size_t)(s * 16 + bb) * 2 + 1) * N + m];
  }
  float M = fmaxf(fmaxf(mv[0], mv[1]), fmaxf(mv[2], mv[3]));
  float wsc[4], denom = 0.f;
#pragma unroll
  for (int s = 0; s < 4; s++) {
    wsc[s] = fexp2(mv[s] - M);
    denom = fmaf(wsc[s], lv[s], denom);
  }
  float inv = 1.0f / denom;
#pragma unroll
  for (int s = 0; s < 4; s++)
    wcb[(size_t)(s * 16 + bb) * N + m] = wsc[s] * inv;
}

// ---------------- combine partials -> d_out ----------------
__global__ __launch_bounds__(256) void comb_kernel(const float* __restrict__ o_part,
                                                   const float* __restrict__ wcb,
                                                   float* __restrict__ out) {
  int i = blockIdx.x * 256 + threadIdx.x;
  int m4 = i & 1023, d = (i >> 10) & 63, bb = i >> 16;
  int kbr = bb >> 2, b = bb & 3;
  float4 acc = make_float4(0.f, 0.f, 0.f, 0.f);
#pragma unroll
  for (int s = 0; s < 4; s++) {
    const float4 o = *(const float4*)(o_part + ((size_t)(s * 16 + bb) * 64 + d) * N + m4 * 4);
    const float4 wv = *(const float4*)(wcb + (size_t)(s * 16 + bb) * N + m4 * 4);
    acc.x = fmaf(o.x, wv.x, acc.x); acc.y = fmaf(o.y, wv.y, acc.y);
    acc.z = fmaf(o.z, wv.z, acc.z); acc.w = fmaf(o.w, wv.w, acc.w);
  }
  *(float4*)(out + ((size_t)(b * 256 + kbr * 64 + d)) * N + m4 * 4) = acc;
}

extern "C" void kernel_launch(void* const* d_in, const int* in_sizes, int n_in,
                              void* d_out, int out_size, void* d_ws, size_t ws_size,
                              hipStream_t stream) {
  const float* x      = (const float*)d_in[0];
  const float* dc_w1  = (const float*)d_in[1];
  const float* dc_g1  = (const float*)d_in[3];
  const float* dc_be1 = (const float*)d_in[4];
  const float* dc_w2  = (const float*)d_in[5];
  const float* dc_g2  = (const float*)d_in[7];
  const float* dc_be2 = (const float*)d_in[8];
  const float* aspp_w[4] = {(const float*)d_in[9],  (const float*)d_in[12],
                            (const float*)d_in[15], (const float*)d_in[18]};
  const float* aspp_g[4] = {(const float*)d_in[10], (const float*)d_in[13],
                            (const float*)d_in[16], (const float*)d_in[19]};
  const float* aspp_b[4] = {(const float*)d_in[11], (const float*)d_in[14],
                            (const float*)d_in[17], (const float*)d_in[20]};
  const float* wq = (const float*)d_in[21];
  const float* bq = (const float*)d_in[22];
  const float* wk = (const float*)d_in[23];
  const float* bk = (const float*)d_in[24];
  const float* wv = (const float*)d_in[25];
  const float* bv = (const float*)d_in[26];
  const float* rel_h = (const float*)d_in[27];
  const float* rel_w = (const float*)d_in[28];
  float* out = (float*)d_out;

  float* ws = (float*)d_ws;
  size_t off = 0;
  auto alloc = [&](size_t nf) { float* p = ws + off; off += nf; return p; };
  unsigned short* Pp1 = (unsigned short*)alloc((size_t)4 * 66 * 66 * 128 / 2 + 64);
  unsigned short* Pp2 = (unsigned short*)alloc((size_t)4 * 66 * 66 * 256 / 2 + 64);
  unsigned short* Pp3 = (unsigned short*)alloc((size_t)4 * 82 * 82 * 256 / 2 + 64);
  const size_t HALF = (size_t)4 * 256 * N;
  float* t1   = alloc(2 * HALF);                   // dc conv ci-split partials
  const size_t BHALF = (size_t)16 * 64 * N;
  float* brp  = alloc(2 * BHALF);                  // branch ci-split partials
  float* st1  = alloc(512);
  float* st2  = alloc(512);
  float* sta  = alloc(512);
  unsigned short* qT    = (unsigned short*)alloc((size_t)16 * N * 64 / 2);
  unsigned short* kT    = (unsigned short*)alloc((size_t)16 * N * 64 / 2);
  unsigned short* vb    = (unsigned short*)alloc((size_t)16 * N * 64 / 2);
  unsigned short* posT  = (unsigned short*)alloc((size_t)N * 64 / 2);
  unsigned short* wt1   = (unsigned short*)alloc((size_t)9 * 256 * 128 / 2);
  unsigned short* wt2   = (unsigned short*)alloc((size_t)9 * 256 * 256 / 2);
  unsigned short* wtbr  = (unsigned short*)alloc((size_t)4 * 9 * 64 * 256 / 2);
  float* o_part = alloc((size_t)4 * 16 * 64 * N);  // 67 MB
  float* mlb    = alloc((size_t)4 * 16 * 2 * N);
  float* wcb    = alloc((size_t)4 * 16 * N);

  hipMemsetAsync(Pp1, 0, (size_t)4 * 66 * 66 * 128 * 2, stream);
  hipMemsetAsync(Pp2, 0, (size_t)4 * 66 * 66 * 256 * 2, stream);
  hipMemsetAsync(Pp3, 0, (size_t)4 * 82 * 82 * 256 * 2, stream);
  hipMemsetAsync(wtbr, 0, (size_t)4 * 9 * 64 * 256 * 2, stream);

  // weight prep
  wtr_kernel<<<(9 * 256 * 128) / 256, 256, 0, stream>>>(dc_w1, wt1, 256, 128, 9);
  wtr_kernel<<<(9 * 256 * 256) / 256, 256, 0, stream>>>(dc_w2, wt2, 256, 256, 9);
  wtr_kernel<<<(64 * 256) / 256, 256, 0, stream>>>(
      aspp_w[0], wtbr + (size_t)4 * 64 * 256, 64, 256, 1);
  for (int kbr = 1; kbr < 4; kbr++)
    wtr_kernel<<<(9 * 64 * 256) / 256, 256, 0, stream>>>(
        aspp_w[kbr], wtbr + (size_t)kbr * 9 * 64 * 256, 64, 256, 9);

  pool_kernel<<<2048, 256, 0, stream>>>(x, Pp1);

  dcconv_kernel<128><<<dim3(32, 4, 8), 256, 0, stream>>>(Pp1, wt1, t1);
  bn_stats2_kernel<<<256, 256, 0, stream>>>(t1, t1 + HALF, dc_g1, dc_be1, st1, 256);
  bn_norm_pad2_kernel<<<4096, 256, 0, stream>>>(t1, t1 + HALF, st1, Pp2, 66, 1);
  dcconv_kernel<256><<<dim3(32, 4, 8), 256, 0, stream>>>(Pp2, wt2, t1);
  bn_stats2_kernel<<<256, 256, 0, stream>>>(t1, t1 + HALF, dc_g2, dc_be2, st2, 256);
  bn_norm_pad2_kernel<<<4096, 256, 0, stream>>>(t1, t1 + HALF, st2, Pp3, 82, 9);

  branch2_kernel<<<dim3(32, 16, 2), 256, 0, stream>>>(Pp3, wtbr, brp);
  for (int kbr = 0; kbr < 4; kbr++) {
    const size_t koff = (size_t)kbr * 4 * 64 * N;
    bn_stats2_kernel<<<64, 256, 0, stream>>>(brp + koff, brp + BHALF + koff,
                                             aspp_g[kbr], aspp_b[kbr],
                                             sta + kbr * 128, 64);
    bn_norm2_kernel<<<4096, 256, 0, stream>>>(brp + koff, brp + BHALF + koff,
                                              sta + kbr * 128);
  }

  qkv_kernel<<<dim3(16, 12, 16), 256, 0, stream>>>(brp, wq, bq, wk, bk, wv, bv,
                                                   qT, kT, vb);
  posT_kernel<<<256, 256, 0, stream>>>(rel_h, rel_w, posT);

  flash3_kernel<<<dim3(32, 16, 4), 256, 0, stream>>>(qT, kT, posT, vb, o_part, mlb);
  wcomb_kernel<<<256, 256, 0, stream>>>(mlb, wcb);
  comb_kernel<<<4096, 256, 0, stream>>>(o_part, wcb, out);
}